// Round 1
// baseline (759.331 us; speedup 1.0000x reference)
//
#include <hip/hip_runtime.h>
#include <hip/hip_bf16.h>

typedef __attribute__((ext_vector_type(8))) short short8;
typedef __attribute__((ext_vector_type(4))) float float4_t;

#define HW 4096
#define CC 256
#define NBATCH 4

static __device__ __forceinline__ unsigned short f2b(float f) {
    union { float f; unsigned u; } v; v.f = f;
    unsigned r = v.u + 0x7FFF + ((v.u >> 16) & 1);   // RNE
    return (unsigned short)(r >> 16);
}

// ---- kernel 0: fp32 weights -> bf16 (3 x 256x256) ----
__global__ void k_cvt(const float* __restrict__ a, const float* __restrict__ b,
                      const float* __restrict__ c, unsigned short* __restrict__ da,
                      unsigned short* __restrict__ db, unsigned short* __restrict__ dc) {
    int i = blockIdx.x * 256 + threadIdx.x;          // grid 768 -> 196608 elems
    int sel = i >> 16, off = i & 65535;
    const float* s = sel == 0 ? a : (sel == 1 ? b : c);
    unsigned short* d = sel == 0 ? da : (sel == 1 ? db : dc);
    d[off] = f2b(s[off]);
}

// ---- kernel 1: x[n][c][p] -> XT[n][p][c] (bf16) and gb[n][c][p] (bf16) ----
__global__ __launch_bounds__(256) void k_prep(const float* __restrict__ x,
                                              unsigned short* __restrict__ XT,
                                              unsigned short* __restrict__ gb) {
    __shared__ float T[64][65];
    int n = blockIdx.z, c0 = blockIdx.y * 64, p0 = blockIdx.x * 64;
    int t = threadIdx.x;
    int pl = t & 63, rg = t >> 6;
    const float* xp = x + ((size_t)n * CC + c0) * HW + p0;
    #pragma unroll
    for (int i = 0; i < 16; i++) {
        int cl = rg * 16 + i;
        float v = xp[(size_t)cl * HW + pl];
        T[cl][pl] = v;
        gb[((size_t)n * CC + c0 + cl) * HW + p0 + pl] = f2b(v);
    }
    __syncthreads();
    int cl = t & 63, pg = t >> 6;
    unsigned short* xt = XT + ((size_t)n * HW + p0) * CC + c0;
    #pragma unroll
    for (int i = 0; i < 16; i++) {
        int plw = pg * 16 + i;
        xt[(size_t)plw * CC + cl] = f2b(T[cl][plw]);
    }
}

// ---- kernel 2: projection GEMM  outT[p][co] = sum_ci XT[p][ci]*W[co][ci] + b[co] ----
__global__ __launch_bounds__(256) void k_proj(const unsigned short* __restrict__ XT,
                                              const unsigned short* __restrict__ Wt,
                                              const unsigned short* __restrict__ Wp,
                                              const float* __restrict__ bt,
                                              const float* __restrict__ bp,
                                              unsigned short* __restrict__ outT_t,
                                              unsigned short* __restrict__ outT_p) {
    const unsigned short* W; const float* b; unsigned short* outT;
    if (blockIdx.y == 0) { W = Wt; b = bt; outT = outT_t; }
    else                 { W = Wp; b = bp; outT = outT_p; }
    int w = threadIdx.x >> 6, lane = threadIdx.x & 63;
    int nidx = lane & 15, quad = lane >> 4;
    size_t row0 = (size_t)blockIdx.x * 64 + w * 16;
    float4_t acc[16];
    #pragma unroll
    for (int i = 0; i < 16; i++) acc[i] = (float4_t)(0.f);
    const unsigned short* arow = XT + (row0 + nidx) * CC + quad * 8;
    for (int ks = 0; ks < 8; ks++) {
        short8 a = *(const short8*)(arow + ks * 32);
        #pragma unroll
        for (int cb = 0; cb < 16; cb++) {
            short8 bb = *(const short8*)(W + (size_t)(cb * 16 + nidx) * CC + ks * 32 + quad * 8);
            acc[cb] = __builtin_amdgcn_mfma_f32_16x16x32_bf16(a, bb, acc[cb], 0, 0, 0);
        }
    }
    #pragma unroll
    for (int cb = 0; cb < 16; cb++) {
        int co = cb * 16 + nidx;
        float bias = b[co];
        #pragma unroll
        for (int r = 0; r < 4; r++) {
            size_t prow = row0 + quad * 4 + r;
            outT[prow * CC + co] = f2b(acc[cb][r] + bias);
        }
    }
}

// ---- kernel 3: flash attention. 1 block = 16 queries; 4 waves split 4096 keys ----
__global__ __launch_bounds__(256) void k_attn(const unsigned short* __restrict__ thetaT,
                                              const unsigned short* __restrict__ phiT,
                                              const unsigned short* __restrict__ gb,
                                              unsigned short* __restrict__ fT) {
    __shared__ __align__(16) unsigned short Pt[4][16][40];
    __shared__ float Obuf[16][256];
    __shared__ float Wm[4][16], Wl[4][16], Linv[16];
    int w = threadIdx.x >> 6, lane = threadIdx.x & 63;
    int nidx = lane & 15, quad = lane >> 4;
    int nb = blockIdx.x >> 8;
    int p0 = (blockIdx.x & 255) * 16;
    size_t seq0 = (size_t)nb * HW;
    for (int i = threadIdx.x; i < 16 * 256; i += 256) ((float*)Obuf)[i] = 0.f;

    short8 aq[8];
    const unsigned short* qrow = thetaT + (seq0 + p0 + nidx) * CC + quad * 8;
    #pragma unroll
    for (int kb = 0; kb < 8; kb++) aq[kb] = *(const short8*)(qrow + kb * 32);

    float4_t o[16];
    #pragma unroll
    for (int i = 0; i < 16; i++) o[i] = (float4_t)(0.f);
    float rowm[4] = {-INFINITY, -INFINITY, -INFINITY, -INFINITY};
    float rowl[4] = {0.f, 0.f, 0.f, 0.f};
    const float L2E = 1.44269504088896340736f;
    const unsigned short* gbase = gb + (size_t)nb * CC * HW;

    for (int kt = 0; kt < 32; kt++) {
        int q0 = w * 1024 + kt * 32;
        float4_t s0 = (float4_t)(0.f), s1 = (float4_t)(0.f);
        const unsigned short* k0p = phiT + (seq0 + q0 + nidx) * CC + quad * 8;
        const unsigned short* k1p = k0p + 16 * CC;
        #pragma unroll
        for (int kb = 0; kb < 8; kb++) {
            short8 b0 = *(const short8*)(k0p + kb * 32);
            short8 b1 = *(const short8*)(k1p + kb * 32);
            s0 = __builtin_amdgcn_mfma_f32_16x16x32_bf16(aq[kb], b0, s0, 0, 0, 0);
            s1 = __builtin_amdgcn_mfma_f32_16x16x32_bf16(aq[kb], b1, s1, 0, 0, 0);
        }
        #pragma unroll
        for (int r = 0; r < 4; r++) {
            float v0 = s0[r] * 0.0625f, v1 = s1[r] * 0.0625f;
            float mx = fmaxf(v0, v1);
            #pragma unroll
            for (int off = 1; off < 16; off <<= 1) mx = fmaxf(mx, __shfl_xor(mx, off));
            float nm = fmaxf(rowm[r], mx);
            float alpha = exp2f((rowm[r] - nm) * L2E);
            float pv0 = exp2f((v0 - nm) * L2E);
            float pv1 = exp2f((v1 - nm) * L2E);
            rowm[r] = nm;
            float rs = pv0 + pv1;
            #pragma unroll
            for (int off = 1; off < 16; off <<= 1) rs += __shfl_xor(rs, off);
            rowl[r] = rowl[r] * alpha + rs;
            #pragma unroll
            for (int cb = 0; cb < 16; cb++) o[cb][r] *= alpha;
            int row = quad * 4 + r;
            Pt[w][row][nidx] = f2b(pv0);
            Pt[w][row][16 + nidx] = f2b(pv1);
        }
        asm volatile("s_waitcnt lgkmcnt(0)" ::: "memory");
        short8 ap = *(const short8*)(&Pt[w][nidx][quad * 8]);
        #pragma unroll
        for (int cb = 0; cb < 16; cb++) {
            short8 bv = *(const short8*)(gbase + (size_t)(cb * 16 + nidx) * HW + q0 + quad * 8);
            o[cb] = __builtin_amdgcn_mfma_f32_16x16x32_bf16(ap, bv, o[cb], 0, 0, 0);
        }
    }

    if (nidx == 0) {
        #pragma unroll
        for (int r = 0; r < 4; r++) { Wm[w][quad * 4 + r] = rowm[r]; Wl[w][quad * 4 + r] = rowl[r]; }
    }
    __syncthreads();
    float scale[4];
    #pragma unroll
    for (int r = 0; r < 4; r++) {
        int row = quad * 4 + r;
        float gm = fmaxf(fmaxf(Wm[0][row], Wm[1][row]), fmaxf(Wm[2][row], Wm[3][row]));
        scale[r] = exp2f((rowm[r] - gm) * L2E);
    }
    if (threadIdx.x < 16) {
        int row = threadIdx.x;
        float gm = fmaxf(fmaxf(Wm[0][row], Wm[1][row]), fmaxf(Wm[2][row], Wm[3][row]));
        float L = 0.f;
        #pragma unroll
        for (int ww = 0; ww < 4; ww++) L += Wl[ww][row] * exp2f((Wm[ww][row] - gm) * L2E);
        Linv[row] = 1.0f / L;
    }
    #pragma unroll
    for (int cb = 0; cb < 16; cb++) {
        #pragma unroll
        for (int r = 0; r < 4; r++) {
            atomicAdd(&Obuf[quad * 4 + r][cb * 16 + nidx], o[cb][r] * scale[r]);
        }
    }
    __syncthreads();
    unsigned short* frow = fT + (seq0 + p0) * CC;
    for (int row = 0; row < 16; row++) {
        frow[(size_t)row * CC + threadIdx.x] = f2b(Obuf[row][threadIdx.x] * Linv[row]);
    }
}

// ---- kernel 4: out[n][co][p] = x + b[co] + sum_k W[co][k]*fT[p][k] ----
__global__ __launch_bounds__(256) void k_final(const unsigned short* __restrict__ Wc,
                                               const float* __restrict__ bc,
                                               const unsigned short* __restrict__ fT,
                                               const float* __restrict__ x,
                                               float* __restrict__ out) {
    int w = threadIdx.x >> 6, lane = threadIdx.x & 63;
    int nidx = lane & 15, quad = lane >> 4;
    int n = blockIdx.z;
    int co0 = blockIdx.y * 64 + w * 16;
    int p0 = blockIdx.x * 64;
    float4_t acc[4];
    #pragma unroll
    for (int i = 0; i < 4; i++) acc[i] = (float4_t)(0.f);
    const unsigned short* arow = Wc + (size_t)(co0 + nidx) * CC + quad * 8;
    const unsigned short* brow = fT + ((size_t)n * HW + p0 + nidx) * CC + quad * 8;
    for (int ks = 0; ks < 8; ks++) {
        short8 a = *(const short8*)(arow + ks * 32);
        #pragma unroll
        for (int pb = 0; pb < 4; pb++) {
            short8 bb = *(const short8*)(brow + (size_t)pb * 16 * CC + ks * 32);
            acc[pb] = __builtin_amdgcn_mfma_f32_16x16x32_bf16(a, bb, acc[pb], 0, 0, 0);
        }
    }
    #pragma unroll
    for (int pb = 0; pb < 4; pb++) {
        #pragma unroll
        for (int r = 0; r < 4; r++) {
            int co = co0 + quad * 4 + r;
            size_t idx = ((size_t)n * CC + co) * HW + p0 + pb * 16 + nidx;
            out[idx] = x[idx] + bc[co] + acc[pb][r];
        }
    }
}

extern "C" void kernel_launch(void* const* d_in, const int* in_sizes, int n_in,
                              void* d_out, int out_size, void* d_ws, size_t ws_size,
                              hipStream_t stream) {
    const float* x       = (const float*)d_in[0];
    const float* theta_w = (const float*)d_in[1];
    const float* theta_b = (const float*)d_in[2];
    const float* phi_w   = (const float*)d_in[3];
    const float* phi_b   = (const float*)d_in[4];
    const float* conv1_w = (const float*)d_in[5];
    const float* conv1_b = (const float*)d_in[6];
    float* out = (float*)d_out;

    const size_t SEQ = (size_t)NBATCH * HW;       // 16384
    unsigned short* XT  = (unsigned short*)d_ws;  // [SEQ][256]
    unsigned short* gb  = XT  + SEQ * CC;         // [N][256][4096]
    unsigned short* thT = gb  + SEQ * CC;         // [SEQ][256]
    unsigned short* phT = thT + SEQ * CC;         // [SEQ][256]
    unsigned short* fT  = phT + SEQ * CC;         // [SEQ][256]
    unsigned short* Wbt = fT  + SEQ * CC;
    unsigned short* Wbp = Wbt + 65536;
    unsigned short* Wbc = Wbp + 65536;

    k_cvt<<<dim3(768), 256, 0, stream>>>(theta_w, phi_w, conv1_w, Wbt, Wbp, Wbc);
    k_prep<<<dim3(64, 4, 4), 256, 0, stream>>>(x, XT, gb);
    k_proj<<<dim3(256, 2), 256, 0, stream>>>(XT, Wbt, Wbp, theta_b, phi_b, thT, phT);
    k_attn<<<dim3(1024), 256, 0, stream>>>(thT, phT, gb, fT);
    k_final<<<dim3(64, 4, 4), 256, 0, stream>>>(Wbc, conv1_b, fT, x, out);
}

// Round 2
// 284.385 us; speedup vs baseline: 2.6701x; 2.6701x over previous
//
#include <hip/hip_runtime.h>
#include <hip/hip_bf16.h>

typedef __attribute__((ext_vector_type(8))) short short8;
typedef __attribute__((ext_vector_type(4))) float float4_t;
typedef unsigned short ushort;

#define HW 4096
#define CC 256
#define NBATCH 4

#define GLDS(g, l) __builtin_amdgcn_global_load_lds( \
    (const __attribute__((address_space(1))) void*)(g), \
    (__attribute__((address_space(3))) void*)(l), 16, 0, 0)

static __device__ __forceinline__ unsigned short f2b(float f) {
    union { float f; unsigned u; } v; v.f = f;
    unsigned r = v.u + 0x7FFF + ((v.u >> 16) & 1);   // RNE
    return (unsigned short)(r >> 16);
}

// ---- kernel 0: fp32 weights -> bf16 (3 x 256x256) ----
__global__ void k_cvt(const float* __restrict__ a, const float* __restrict__ b,
                      const float* __restrict__ c, unsigned short* __restrict__ da,
                      unsigned short* __restrict__ db, unsigned short* __restrict__ dc) {
    int i = blockIdx.x * 256 + threadIdx.x;          // grid 768 -> 196608 elems
    int sel = i >> 16, off = i & 65535;
    const float* s = sel == 0 ? a : (sel == 1 ? b : c);
    unsigned short* d = sel == 0 ? da : (sel == 1 ? db : dc);
    d[off] = f2b(s[off]);
}

// ---- kernel 1: x[n][c][p] -> XT[n][p][c] (bf16) and gb[n][c][p] (bf16) ----
__global__ __launch_bounds__(256) void k_prep(const float* __restrict__ x,
                                              unsigned short* __restrict__ XT,
                                              unsigned short* __restrict__ gb) {
    __shared__ float T[64][65];
    int n = blockIdx.z, c0 = blockIdx.y * 64, p0 = blockIdx.x * 64;
    int t = threadIdx.x;
    int pl = t & 63, rg = t >> 6;
    const float* xp = x + ((size_t)n * CC + c0) * HW + p0;
    #pragma unroll
    for (int i = 0; i < 16; i++) {
        int cl = rg * 16 + i;
        float v = xp[(size_t)cl * HW + pl];
        T[cl][pl] = v;
        gb[((size_t)n * CC + c0 + cl) * HW + p0 + pl] = f2b(v);
    }
    __syncthreads();
    int cl = t & 63, pg = t >> 6;
    unsigned short* xt = XT + ((size_t)n * HW + p0) * CC + c0;
    #pragma unroll
    for (int i = 0; i < 16; i++) {
        int plw = pg * 16 + i;
        xt[(size_t)plw * CC + cl] = f2b(T[cl][plw]);
    }
}

// ---- kernel 2: projection GEMM  outT[p][co] = sum_ci XT[p][ci]*W[co][ci] + b[co] ----
__global__ __launch_bounds__(256) void k_proj(const unsigned short* __restrict__ XT,
                                              const unsigned short* __restrict__ Wt,
                                              const unsigned short* __restrict__ Wp,
                                              const float* __restrict__ bt,
                                              const float* __restrict__ bp,
                                              unsigned short* __restrict__ outT_t,
                                              unsigned short* __restrict__ outT_p) {
    const unsigned short* W; const float* b; unsigned short* outT;
    if (blockIdx.y == 0) { W = Wt; b = bt; outT = outT_t; }
    else                 { W = Wp; b = bp; outT = outT_p; }
    int w = threadIdx.x >> 6, lane = threadIdx.x & 63;
    int nidx = lane & 15, quad = lane >> 4;
    size_t row0 = (size_t)blockIdx.x * 64 + w * 16;
    float4_t acc[16];
    #pragma unroll
    for (int i = 0; i < 16; i++) acc[i] = (float4_t)(0.f);
    const unsigned short* arow = XT + (row0 + nidx) * CC + quad * 8;
    for (int ks = 0; ks < 8; ks++) {
        short8 a = *(const short8*)(arow + ks * 32);
        #pragma unroll
        for (int cb = 0; cb < 16; cb++) {
            short8 bb = *(const short8*)(W + (size_t)(cb * 16 + nidx) * CC + ks * 32 + quad * 8);
            acc[cb] = __builtin_amdgcn_mfma_f32_16x16x32_bf16(a, bb, acc[cb], 0, 0, 0);
        }
    }
    #pragma unroll
    for (int cb = 0; cb < 16; cb++) {
        int co = cb * 16 + nidx;
        float bias = b[co];
        #pragma unroll
        for (int r = 0; r < 4; r++) {
            size_t prow = row0 + quad * 4 + r;
            outT[prow * CC + co] = f2b(acc[cb][r] + bias);
        }
    }
}

// ---- kernel 3: flash attention, no-max softmax.
// 1 block = 64 queries (4 waves x 16 q-rows); sweep 4096 keys in 128 tiles of 32.
// K staged reg->LDS (544B padded stride, bank-uniform); V staged via global_load_lds
// (natural [ch][key32] layout is bank-uniform); double-buffered, 1 barrier/tile.
__global__ __launch_bounds__(256) void k_attn(const unsigned short* __restrict__ thetaT,
                                              const unsigned short* __restrict__ phiT,
                                              const unsigned short* __restrict__ gb,
                                              unsigned short* __restrict__ fT) {
    __shared__ __align__(16) ushort Kbuf[2][32][272];   // 272 = 256 + 16 pad -> 544B stride
    __shared__ __align__(16) ushort Vbuf[2][256][32];   // [ch][key]
    __shared__ __align__(16) ushort Pt[4][16][40];
    __shared__ __align__(16) ushort Obf[64][256];
    const int tid = threadIdx.x;
    const int w = tid >> 6, lane = tid & 63;
    const int nidx = lane & 15, quad = lane >> 4;
    // XCD swizzle: batch nb pinned to XCD pair {2nb,2nb+1} (assuming bx%8 round-robin)
    const int nb = (blockIdx.x & 7) >> 1;
    const int tile = ((blockIdx.x >> 3) << 1) | (blockIdx.x & 1);
    const int p0 = tile * 64;
    const size_t seq0 = (size_t)nb * HW;
    const ushort* Kg = phiT + seq0 * CC;                 // [4096][256]
    const ushort* Vg = gb + (size_t)nb * CC * HW;        // [256][4096]

    // persistent theta A-frags: 16 queries per wave, full K=256
    short8 aq[8];
    {
        const ushort* qrow = thetaT + (seq0 + p0 + w * 16 + nidx) * CC + quad * 8;
        #pragma unroll
        for (int kb = 0; kb < 8; kb++) aq[kb] = *(const short8*)(qrow + kb * 32);
    }

    float4_t o[16];
    #pragma unroll
    for (int i = 0; i < 16; i++) o[i] = (float4_t)(0.f);
    float rowl[4] = {0.f, 0.f, 0.f, 0.f};

    const int krow = w * 8 + (lane >> 5);                // +i*2 per chunk
    const int kcol = (lane & 31) * 8;
    short8 kreg[4];
    // ---- prologue: prefetch tile 0 ----
    #pragma unroll
    for (int i = 0; i < 4; i++)
        kreg[i] = *(const short8*)(Kg + (size_t)(krow + i * 2) * CC + kcol);
    #pragma unroll
    for (int i = 0; i < 4; i++) {
        int ch = (w * 4 + i) * 16 + (lane >> 2);
        GLDS(Vg + (size_t)ch * HW + (lane & 3) * 8, &Vbuf[0][0][0] + (w * 4 + i) * 512);
    }

    const float SC = 0.0625f * 1.44269504088896f;        // /sqrt(256) * log2(e)
    #pragma unroll 2
    for (int t = 0; t < 128; t++) {
        const int buf = t & 1;
        asm volatile("s_waitcnt vmcnt(0)" ::: "memory"); // K regs + V dma for tile t done
        #pragma unroll
        for (int i = 0; i < 4; i++)
            *(short8*)(&Kbuf[buf][krow + i * 2][kcol]) = kreg[i];
        __syncthreads();                                  // buffers for tile t ready
        if (t < 127) {                                    // prefetch t+1 (overlaps compute)
            const int k0n = (t + 1) * 32;
            #pragma unroll
            for (int i = 0; i < 4; i++)
                kreg[i] = *(const short8*)(Kg + (size_t)(k0n + krow + i * 2) * CC + kcol);
            #pragma unroll
            for (int i = 0; i < 4; i++) {
                int ch = (w * 4 + i) * 16 + (lane >> 2);
                GLDS(Vg + (size_t)ch * HW + k0n + (lane & 3) * 8,
                     &Vbuf[buf ^ 1][0][0] + (w * 4 + i) * 512);
            }
        }
        // ---- QK^T over this 32-key tile ----
        float4_t s0 = (float4_t)(0.f), s1 = (float4_t)(0.f);
        #pragma unroll
        for (int kb = 0; kb < 8; kb++) {
            short8 b0 = *(const short8*)(&Kbuf[buf][nidx][kb * 32 + quad * 8]);
            short8 b1 = *(const short8*)(&Kbuf[buf][16 + nidx][kb * 32 + quad * 8]);
            s0 = __builtin_amdgcn_mfma_f32_16x16x32_bf16(aq[kb], b0, s0, 0, 0, 0);
            s1 = __builtin_amdgcn_mfma_f32_16x16x32_bf16(aq[kb], b1, s1, 0, 0, 0);
        }
        // ---- no-max softmax: P = exp(s/16), per-lane row partial sums ----
        #pragma unroll
        for (int r = 0; r < 4; r++) {
            float p0v = exp2f(s0[r] * SC);
            float p1v = exp2f(s1[r] * SC);
            rowl[r] += p0v + p1v;
            Pt[w][quad * 4 + r][nidx] = f2b(p0v);
            Pt[w][quad * 4 + r][16 + nidx] = f2b(p1v);
        }
        asm volatile("s_waitcnt lgkmcnt(0)" ::: "memory");
        short8 ap = *(const short8*)(&Pt[w][nidx][quad * 8]);
        // ---- P @ V ----
        #pragma unroll
        for (int cb = 0; cb < 16; cb++) {
            short8 bv = *(const short8*)(&Vbuf[buf][cb * 16 + nidx][quad * 8]);
            o[cb] = __builtin_amdgcn_mfma_f32_16x16x32_bf16(ap, bv, o[cb], 0, 0, 0);
        }
    }
    // ---- epilogue: row-sum reduce, normalize, coalesced store ----
    float linv[4];
    #pragma unroll
    for (int r = 0; r < 4; r++) {
        float v = rowl[r];
        #pragma unroll
        for (int off = 1; off < 16; off <<= 1) v += __shfl_xor(v, off);
        linv[r] = 1.0f / v;
    }
    #pragma unroll
    for (int cb = 0; cb < 16; cb++)
        #pragma unroll
        for (int r = 0; r < 4; r++)
            Obf[w * 16 + quad * 4 + r][cb * 16 + nidx] = f2b(o[cb][r] * linv[r]);
    __syncthreads();
    ushort* dst = fT + (seq0 + p0) * CC;
    const ushort* src = &Obf[0][0];
    #pragma unroll
    for (int i = 0; i < 8; i++) {
        int idx = i * 256 + tid;
        *(short8*)(dst + (size_t)idx * 8) = *(const short8*)(src + idx * 8);
    }
}

// ---- kernel 4: out[n][co][p] = x + b[co] + sum_k W[co][k]*fT[p][k] ----
__global__ __launch_bounds__(256) void k_final(const unsigned short* __restrict__ Wc,
                                               const float* __restrict__ bc,
                                               const unsigned short* __restrict__ fT,
                                               const float* __restrict__ x,
                                               float* __restrict__ out) {
    int w = threadIdx.x >> 6, lane = threadIdx.x & 63;
    int nidx = lane & 15, quad = lane >> 4;
    int n = blockIdx.z;
    int co0 = blockIdx.y * 64 + w * 16;
    int p0 = blockIdx.x * 64;
    float4_t acc[4];
    #pragma unroll
    for (int i = 0; i < 4; i++) acc[i] = (float4_t)(0.f);
    const unsigned short* arow = Wc + (size_t)(co0 + nidx) * CC + quad * 8;
    const unsigned short* brow = fT + ((size_t)n * HW + p0 + nidx) * CC + quad * 8;
    for (int ks = 0; ks < 8; ks++) {
        short8 a = *(const short8*)(arow + ks * 32);
        #pragma unroll
        for (int pb = 0; pb < 4; pb++) {
            short8 bb = *(const short8*)(brow + (size_t)pb * 16 * CC + ks * 32);
            acc[pb] = __builtin_amdgcn_mfma_f32_16x16x32_bf16(a, bb, acc[pb], 0, 0, 0);
        }
    }
    #pragma unroll
    for (int pb = 0; pb < 4; pb++) {
        #pragma unroll
        for (int r = 0; r < 4; r++) {
            int co = co0 + quad * 4 + r;
            size_t idx = ((size_t)n * CC + co) * HW + p0 + pb * 16 + nidx;
            out[idx] = x[idx] + bc[co] + acc[pb][r];
        }
    }
}

extern "C" void kernel_launch(void* const* d_in, const int* in_sizes, int n_in,
                              void* d_out, int out_size, void* d_ws, size_t ws_size,
                              hipStream_t stream) {
    const float* x       = (const float*)d_in[0];
    const float* theta_w = (const float*)d_in[1];
    const float* theta_b = (const float*)d_in[2];
    const float* phi_w   = (const float*)d_in[3];
    const float* phi_b   = (const float*)d_in[4];
    const float* conv1_w = (const float*)d_in[5];
    const float* conv1_b = (const float*)d_in[6];
    float* out = (float*)d_out;

    const size_t SEQ = (size_t)NBATCH * HW;       // 16384
    unsigned short* XT  = (unsigned short*)d_ws;  // [SEQ][256]
    unsigned short* gb  = XT  + SEQ * CC;         // [N][256][4096]
    unsigned short* thT = gb  + SEQ * CC;         // [SEQ][256]
    unsigned short* phT = thT + SEQ * CC;         // [SEQ][256]
    unsigned short* fT  = phT + SEQ * CC;         // [SEQ][256]
    unsigned short* Wbt = fT  + SEQ * CC;
    unsigned short* Wbp = Wbt + 65536;
    unsigned short* Wbc = Wbp + 65536;

    k_cvt<<<dim3(768), 256, 0, stream>>>(theta_w, phi_w, conv1_w, Wbt, Wbp, Wbc);
    k_prep<<<dim3(64, 4, 4), 256, 0, stream>>>(x, XT, gb);
    k_proj<<<dim3(256, 2), 256, 0, stream>>>(XT, Wbt, Wbp, theta_b, phi_b, thT, phT);
    k_attn<<<dim3(256), 256, 0, stream>>>(thT, phT, gb, fT);
    k_final<<<dim3(64, 4, 4), 256, 0, stream>>>(Wbc, conv1_b, fT, x, out);
}